// Round 5
// baseline (1911.780 us; speedup 1.0000x reference)
//
#include <hip/hip_runtime.h>
#include <hip/hip_bf16.h>
#include <math.h>

#define CD 128
#define HH 4
#define DH 32
#define LL 2

using bf16 = __hip_bfloat16;

__device__ __forceinline__ float bfbits2f(unsigned int s) {
  return __uint_as_float(s << 16);
}

__device__ __forceinline__ float gelu_f(float x) {
  return 0.5f * x * (1.0f + erff(x * 0.70710678118654752f));
}

// ---- detect input formats: flags[0]=floats-are-f32, flags[1]=edge-index-is-i64 ----
__global__ void k_detect(const void* __restrict__ x, const int* __restrict__ ei,
                         int* __restrict__ flags) {
  __shared__ int cnt_f32, cnt_i32;
  if (threadIdx.x == 0) { cnt_f32 = 0; cnt_i32 = 0; }
  __syncthreads();
  int t = threadIdx.x;  // 128 threads
  unsigned short u = ((const unsigned short*)x)[2 * t];
  float v = bfbits2f((unsigned int)u);
  float av = fabsf(v);
  if (av != 0.f && (av > 1e8f || av < 1e-8f)) atomicAdd(&cnt_f32, 1);
  if (t < 64) {
    if (((const int*)ei)[2 * t + 1] != 0) atomicAdd(&cnt_i32, 1);
  }
  __syncthreads();
  if (threadIdx.x == 0) {
    flags[0] = (cnt_f32 > 8) ? 1 : 0;
    flags[1] = (cnt_i32 == 0) ? 1 : 0;
  }
}

// ---- normalize a float input (bf16 or f32) to f32 ----
__global__ void k_cvt(const void* __restrict__ in, float* __restrict__ out, int n,
                      const int* __restrict__ flags) {
  int i = blockIdx.x * blockDim.x + threadIdx.x;
  if (i >= n) return;
  if (flags[0]) out[i] = ((const float*)in)[i];
  else out[i] = bfbits2f((unsigned int)((const unsigned short*)in)[i]);
}

// ---- all parameter tensors -> contiguous f32 block, one launch ----
#define NSEG 14
struct SegTab {
  const void* src[NSEG];
  int off[NSEG];  // cumulative start offset in dst
  int total;
};
__global__ void k_cvt_params(SegTab tab, float* __restrict__ dst,
                             const int* __restrict__ flags) {
  int i = blockIdx.x * 256 + threadIdx.x;
  if (i >= tab.total) return;
  int seg = 0;
#pragma unroll
  for (int k = 1; k < NSEG; k++)
    if (i >= tab.off[k]) seg = k;
  int j = i - tab.off[seg];
  const void* src = tab.src[seg];
  dst[i] = flags[0] ? ((const float*)src)[j]
                    : bfbits2f((unsigned int)((const unsigned short*)src)[j]);
}

__device__ __forceinline__ int edge_idx(const int* __restrict__ ei, long pos, int is64) {
  return is64 ? ei[2 * pos] : ei[pos];
}

// ---- fold relation transforms into K/V weights+biases, both layers, one launch ----
// grid (CD+1, HH, LL*2); block DH. x==CD computes the bias row.
__global__ void k_eff(const float* __restrict__ Wk, const float* __restrict__ bk,
                      const float* __restrict__ Wv, const float* __restrict__ bv,
                      const float* __restrict__ ar, const float* __restrict__ mr,
                      float* __restrict__ wke, float* __restrict__ bke,
                      float* __restrict__ wve, float* __restrict__ bve) {
  int c = blockIdx.x, h = blockIdx.y, z = blockIdx.z;
  int l = z >> 1, which = z & 1;
  int e = threadIdx.x;
  const float* W = (which ? Wv : Wk) + (size_t)l * CD * CD;
  const float* B = (which ? bv : bk) + (size_t)l * CD;
  const float* R = (which ? mr : ar) + (size_t)l * HH * DH * DH + h * DH * DH;
  float* Wo = (which ? wve : wke) + (size_t)l * CD * CD;
  float* Bo = (which ? bve : bke) + (size_t)l * CD;
  float acc = 0.f;
  if (c < CD) {
#pragma unroll
    for (int d = 0; d < DH; d++) acc += W[c * CD + h * DH + d] * R[d * DH + e];
    Wo[c * CD + h * DH + e] = acc;
  } else {
#pragma unroll
    for (int d = 0; d < DH; d++) acc += B[h * DH + d] * R[d * DH + e];
    Bo[h * DH + e] = acc;
  }
}

// ==== fused q/k/v projection: one x-tile staging, 3 weight passes ====
__global__ __launch_bounds__(256) void k_gemm3(
    const float* __restrict__ xin,
    const float* __restrict__ w0, const float* __restrict__ b0, float* __restrict__ y0,
    const float* __restrict__ w1, const float* __restrict__ b1, float* __restrict__ y1,
    const float* __restrict__ w2, const float* __restrict__ b2, float* __restrict__ y2,
    int nrows) {
  __shared__ float xs[128][CD];
  const int t = threadIdx.x;
  const int r0 = blockIdx.x * 128;
#pragma unroll
  for (int it = 0; it < 16; it++) {
    int idx = t + it * 256;
    int r = idx >> 5;
    int c4 = (idx & 31) * 4;
    int gr = r0 + r;
    float4 f = make_float4(0.f, 0.f, 0.f, 0.f);
    if (gr < nrows) f = *(const float4*)(xin + (size_t)gr * CD + c4);
    *(float4*)&xs[r][c4] = f;
  }
  __syncthreads();
  const int tx = t & 31, ty = t >> 5;  // thread covers cols 4tx..4tx+3, rows ty*16..+15
  const float* ws[3] = {w0, w1, w2};
  const float* bs[3] = {b0, b1, b2};
  float* ys[3] = {y0, y1, y2};
#pragma unroll
  for (int sI = 0; sI < 3; sI++) {
    const float* win = ws[sI];
    float4 bv = *(const float4*)(bs[sI] + 4 * tx);
    float4 acc[16];
#pragma unroll
    for (int rr = 0; rr < 16; rr++) acc[rr] = bv;
    for (int k4 = 0; k4 < CD; k4 += 4) {
      float4 wv0 = *(const float4*)(win + (size_t)(k4 + 0) * CD + 4 * tx);
      float4 wv1 = *(const float4*)(win + (size_t)(k4 + 1) * CD + 4 * tx);
      float4 wv2 = *(const float4*)(win + (size_t)(k4 + 2) * CD + 4 * tx);
      float4 wv3 = *(const float4*)(win + (size_t)(k4 + 3) * CD + 4 * tx);
#pragma unroll
      for (int rr = 0; rr < 16; rr++) {
        float4 xv = *(const float4*)&xs[ty * 16 + rr][k4];
        acc[rr].x += xv.x * wv0.x + xv.y * wv1.x + xv.z * wv2.x + xv.w * wv3.x;
        acc[rr].y += xv.x * wv0.y + xv.y * wv1.y + xv.z * wv2.y + xv.w * wv3.y;
        acc[rr].z += xv.x * wv0.z + xv.y * wv1.z + xv.z * wv2.z + xv.w * wv3.z;
        acc[rr].w += xv.x * wv0.w + xv.y * wv1.w + xv.z * wv2.w + xv.w * wv3.w;
      }
    }
#pragma unroll
    for (int rr = 0; rr < 16; rr++) {
      int gr = r0 + ty * 16 + rr;
      if (gr < nrows) *(float4*)(ys[sI] + (size_t)gr * CD + 4 * tx) = acc[rr];
    }
  }
}

// ==== gelu(agg) @ Wa + ba, then h = g*out + (1-g)*h, in place ====
__global__ __launch_bounds__(256) void k_gemm_gate(
    const float* __restrict__ agg, const float* __restrict__ win,
    const float* __restrict__ bin, float* __restrict__ h,
    const float* __restrict__ skip, int nrows) {
  __shared__ float xs[128][CD];
  const int t = threadIdx.x;
  const int r0 = blockIdx.x * 128;
#pragma unroll
  for (int it = 0; it < 16; it++) {
    int idx = t + it * 256;
    int r = idx >> 5;
    int c4 = (idx & 31) * 4;
    int gr = r0 + r;
    float4 f = make_float4(0.f, 0.f, 0.f, 0.f);
    if (gr < nrows) f = *(const float4*)(agg + (size_t)gr * CD + c4);
    f.x = gelu_f(f.x); f.y = gelu_f(f.y); f.z = gelu_f(f.z); f.w = gelu_f(f.w);
    *(float4*)&xs[r][c4] = f;
  }
  __syncthreads();
  const int tx = t & 31, ty = t >> 5;
  float4 bv = *(const float4*)(bin + 4 * tx);
  float4 acc[16];
#pragma unroll
  for (int rr = 0; rr < 16; rr++) acc[rr] = bv;
  for (int k4 = 0; k4 < CD; k4 += 4) {
    float4 wv0 = *(const float4*)(win + (size_t)(k4 + 0) * CD + 4 * tx);
    float4 wv1 = *(const float4*)(win + (size_t)(k4 + 1) * CD + 4 * tx);
    float4 wv2 = *(const float4*)(win + (size_t)(k4 + 2) * CD + 4 * tx);
    float4 wv3 = *(const float4*)(win + (size_t)(k4 + 3) * CD + 4 * tx);
#pragma unroll
    for (int rr = 0; rr < 16; rr++) {
      float4 xv = *(const float4*)&xs[ty * 16 + rr][k4];
      acc[rr].x += xv.x * wv0.x + xv.y * wv1.x + xv.z * wv2.x + xv.w * wv3.x;
      acc[rr].y += xv.x * wv0.y + xv.y * wv1.y + xv.z * wv2.y + xv.w * wv3.y;
      acc[rr].z += xv.x * wv0.z + xv.y * wv1.z + xv.z * wv2.z + xv.w * wv3.z;
      acc[rr].w += xv.x * wv0.w + xv.y * wv1.w + xv.z * wv2.w + xv.w * wv3.w;
    }
  }
  float sv = skip[0];
  float gg = 1.f / (1.f + __expf(-sv));
#pragma unroll
  for (int rr = 0; rr < 16; rr++) {
    int gr = r0 + ty * 16 + rr;
    if (gr < nrows) {
      float* hp = h + (size_t)gr * CD + 4 * tx;
      float4 h4 = *(const float4*)hp;
      h4.x = gg * acc[rr].x + (1.f - gg) * h4.x;
      h4.y = gg * acc[rr].y + (1.f - gg) * h4.y;
      h4.z = gg * acc[rr].z + (1.f - gg) * h4.z;
      h4.w = gg * acc[rr].w + (1.f - gg) * h4.w;
      *(float4*)hp = h4;
    }
  }
}

// ==== CSR build ====
__global__ void k_hist(const int* __restrict__ ei, int* __restrict__ deg,
                       const int* __restrict__ flags, int E, int Nn) {
  int i = blockIdx.x * blockDim.x + threadIdx.x;
  if (i >= E) return;
  int d = edge_idx(ei, (long)E + i, flags[1]);
  if ((unsigned)d >= (unsigned)Nn) d = 0;
  atomicAdd(&deg[d], 1);
}

__global__ void k_scan1(const int* __restrict__ deg, int* __restrict__ tmp,
                        int* __restrict__ bsum, int n) {
  __shared__ int sh[256];
  int i = blockIdx.x * 256 + threadIdx.x;
  int v = (i < n) ? deg[i] : 0;
  sh[threadIdx.x] = v;
  __syncthreads();
  for (int off = 1; off < 256; off <<= 1) {
    int t = (threadIdx.x >= off) ? sh[threadIdx.x - off] : 0;
    __syncthreads();
    sh[threadIdx.x] += t;
    __syncthreads();
  }
  if (i < n) tmp[i] = sh[threadIdx.x];
  if (threadIdx.x == 255) bsum[blockIdx.x] = sh[255];
}

__global__ void k_scan2(int* __restrict__ bsum, int nb) {
  __shared__ int sh[256];
  __shared__ int carry;
  if (threadIdx.x == 0) carry = 0;
  __syncthreads();
  for (int base = 0; base < nb; base += 256) {
    int i = base + threadIdx.x;
    int v = (i < nb) ? bsum[i] : 0;
    sh[threadIdx.x] = v;
    __syncthreads();
    for (int off = 1; off < 256; off <<= 1) {
      int t = (threadIdx.x >= off) ? sh[threadIdx.x - off] : 0;
      __syncthreads();
      sh[threadIdx.x] += t;
      __syncthreads();
    }
    if (i < nb) bsum[i] = sh[threadIdx.x] + carry;
    __syncthreads();
    if (threadIdx.x == 0) carry += sh[255];
    __syncthreads();
  }
}

__global__ void k_scan3(const int* __restrict__ tmp, const int* __restrict__ deg,
                        const int* __restrict__ bsum, int* __restrict__ rowptr,
                        int* __restrict__ fill, int n) {
  int i = blockIdx.x * 256 + threadIdx.x;
  if (i >= n) return;
  int off = (blockIdx.x > 0) ? bsum[blockIdx.x - 1] : 0;
  int excl = tmp[i] - deg[i] + off;
  rowptr[i] = excl;
  fill[i] = excl;
}

__global__ void k_scatter(const int* __restrict__ ei, int* __restrict__ fill,
                          int* __restrict__ csr_src, const int* __restrict__ flags,
                          int E, int Nn) {
  int i = blockIdx.x * blockDim.x + threadIdx.x;
  if (i >= E) return;
  int is64 = flags[1];
  int s = edge_idx(ei, i, is64);
  int d = edge_idx(ei, (long)E + i, is64);
  if ((unsigned)s >= (unsigned)Nn) s = 0;
  if ((unsigned)d >= (unsigned)Nn) d = 0;
  int pos = atomicAdd(&fill[d], 1);
  csr_src[pos] = s;
}

// ==== fused attention: 1 wave/node; 4 edge-slots x 16 lanes; lane j: dims 8j..8j+7
// (head j>>2); 2-shfl quad reduce; per-slot online softmax; log-sum-exp merge ====
__global__ __launch_bounds__(256) void k_edge(
    const float* __restrict__ q, const float* __restrict__ kk,
    const float* __restrict__ v, const int* __restrict__ rowptr,
    const int* __restrict__ deg, const int* __restrict__ csr_src,
    const float* __restrict__ p_rel, float* __restrict__ agg, int N) {
  int n = (blockIdx.x * 256 + threadIdx.x) >> 6;
  if (n >= N) return;
  const int lane = threadIdx.x & 63;
  const int g = lane >> 4;   // edge slot 0..3
  const int j = lane & 15;   // dim chunk
  const int start = rowptr[n];
  const int end = start + deg[n];
  const float prl = p_rel[j >> 2] * 0.17677669529663687f;  // 1/sqrt(32)
  const float4 qa = *(const float4*)(q + (size_t)n * CD + 8 * j);
  const float4 qb = *(const float4*)(q + (size_t)n * CD + 8 * j + 4);
  float m = -INFINITY, den = 0.f;
  float acc[8] = {0.f, 0.f, 0.f, 0.f, 0.f, 0.f, 0.f, 0.f};
  for (int e = start + g; e < end; e += 4) {
    int s = csr_src[e];
    const float4* kr = (const float4*)(kk + (size_t)s * CD + 8 * j);
    const float4* vr = (const float4*)(v + (size_t)s * CD + 8 * j);
    float4 ka = kr[0], kb = kr[1];
    float4 va = vr[0], vb = vr[1];
    float pd = qa.x * ka.x + qa.y * ka.y + qa.z * ka.z + qa.w * ka.w +
               qb.x * kb.x + qb.y * kb.y + qb.z * kb.z + qb.w * kb.w;
    pd += __shfl_xor(pd, 1);
    pd += __shfl_xor(pd, 2);
    float a = pd * prl;
    float mn = fmaxf(m, a);
    float sc = __expf(m - mn);  // first iter: exp(-inf) = 0
    float ew = __expf(a - mn);
    acc[0] = acc[0] * sc + ew * va.x; acc[1] = acc[1] * sc + ew * va.y;
    acc[2] = acc[2] * sc + ew * va.z; acc[3] = acc[3] * sc + ew * va.w;
    acc[4] = acc[4] * sc + ew * vb.x; acc[5] = acc[5] * sc + ew * vb.y;
    acc[6] = acc[6] * sc + ew * vb.z; acc[7] = acc[7] * sc + ew * vb.w;
    den = den * sc + ew;
    m = mn;
  }
  // merge the 4 slots (lanes j aligned across groups)
#pragma unroll
  for (int off = 16; off <= 32; off <<= 1) {
    float mo = __shfl_xor(m, off);
    float dno = __shfl_xor(den, off);
    float ao[8];
#pragma unroll
    for (int i = 0; i < 8; i++) ao[i] = __shfl_xor(acc[i], off);
    float mn = fmaxf(m, mo);
    float s1 = (den > 0.f) ? __expf(m - mn) : 0.f;
    float s2 = (dno > 0.f) ? __expf(mo - mn) : 0.f;
#pragma unroll
    for (int i = 0; i < 8; i++) acc[i] = acc[i] * s1 + ao[i] * s2;
    den = den * s1 + dno * s2;
    m = mn;
  }
  if (g == 0) {
    float inv = (den > 0.f) ? 1.f / den : 0.f;
    float4 o0 = make_float4(acc[0] * inv, acc[1] * inv, acc[2] * inv, acc[3] * inv);
    float4 o1 = make_float4(acc[4] * inv, acc[5] * inv, acc[6] * inv, acc[7] * inv);
    *(float4*)(agg + (size_t)n * CD + 8 * j) = o0;
    *(float4*)(agg + (size_t)n * CD + 8 * j + 4) = o1;
  }
}

// ---- out[n,0:2] = h[n,:] @ Wfc + bfc; f32 out if flags[0] else bf16 ----
__global__ __launch_bounds__(256) void k_final(const float* __restrict__ h,
                                               const float* __restrict__ Wfc,
                                               const float* __restrict__ bfc,
                                               void* __restrict__ out,
                                               const int* __restrict__ flags, int N) {
  int g = (blockIdx.x * 256 + threadIdx.x) >> 5;
  int lane = threadIdx.x & 31;
  if (g >= N) return;
  const float* hr = h + (size_t)g * CD;
  float a0 = 0.f, a1 = 0.f;
#pragma unroll
  for (int j = 0; j < 4; j++) {
    float hv = hr[lane + 32 * j];
    a0 += hv * Wfc[(lane + 32 * j) * 2];
    a1 += hv * Wfc[(lane + 32 * j) * 2 + 1];
  }
#pragma unroll
  for (int off = 16; off; off >>= 1) {
    a0 += __shfl_xor(a0, off);
    a1 += __shfl_xor(a1, off);
  }
  if (lane == 0) {
    float o0 = a0 + bfc[0];
    float o1 = a1 + bfc[1];
    if (flags[0]) {
      ((float*)out)[(size_t)g * 2] = o0;
      ((float*)out)[(size_t)g * 2 + 1] = o1;
    } else {
      ((bf16*)out)[(size_t)g * 2] = __float2bfloat16(o0);
      ((bf16*)out)[(size_t)g * 2 + 1] = __float2bfloat16(o1);
    }
  }
}

extern "C" void kernel_launch(void* const* d_in, const int* in_sizes, int n_in,
                              void* d_out, int out_size, void* d_ws, size_t ws_size,
                              hipStream_t stream) {
  const int* ei = (const int*)d_in[1];
  const int N = in_sizes[0] / CD;
  const int E = in_sizes[1] / 2;
  const size_t NC = (size_t)N * CD;
  const int nB = (N + 255) / 256;

  float* p = (float*)d_ws;
  float* hbuf = p;       // NC
  float* qbuf = p + NC;  // NC (q; reused as agg)
  float* kbuf = p + 2 * NC;
  float* vbuf = p + 3 * NC;
  int* ip = (int*)(p + 4 * NC);
  int* deg = ip;
  int* tmp = ip + N;
  int* rowptr = ip + 2 * N;
  int* fill = ip + 3 * N;
  int* bsum = ip + 4 * N;
  int* csr_src = ip + 4 * N + nB;
  float* cur = (float*)(csr_src + E);
  float* wkeff = cur; cur += (size_t)LL * CD * CD;
  float* bkeff = cur; cur += (size_t)LL * CD;
  float* wveff = cur; cur += (size_t)LL * CD * CD;
  float* bveff = cur; cur += (size_t)LL * CD;
  // contiguous normalized-f32 parameter block (order == SegTab order!)
  float* pblock = cur;
  float* pWk = cur; cur += (size_t)LL * CD * CD;
  float* pbk = cur; cur += (size_t)LL * CD;
  float* pWq = cur; cur += (size_t)LL * CD * CD;
  float* pbq = cur; cur += (size_t)LL * CD;
  float* pWv = cur; cur += (size_t)LL * CD * CD;
  float* pbv = cur; cur += (size_t)LL * CD;
  float* par = cur; cur += (size_t)LL * HH * DH * DH;
  float* pmr = cur; cur += (size_t)LL * HH * DH * DH;
  float* ppr = cur; cur += (size_t)LL * HH;
  float* pWa = cur; cur += (size_t)LL * CD * CD;
  float* pba = cur; cur += (size_t)LL * CD;
  float* pskip = cur; cur += LL;
  float* pWfc = cur; cur += (size_t)CD * 2;
  float* pbfc = cur; cur += 2;
  int* flags = (int*)cur;

  k_detect<<<1, 128, 0, stream>>>(d_in[0], ei, flags);
  k_cvt<<<((int)NC + 255) / 256, 256, 0, stream>>>(d_in[0], hbuf, (int)NC, flags);

  // one-launch parameter normalization
  SegTab tab;
  const int sizes[NSEG] = {LL * CD * CD, LL * CD, LL * CD * CD, LL * CD,
                           LL * CD * CD, LL * CD, LL * HH * DH * DH,
                           LL * HH * DH * DH, LL * HH, LL * CD * CD, LL * CD,
                           LL, CD * 2, 2};
  const int srcIdx[NSEG] = {2, 3, 4, 5, 6, 7, 8, 9, 10, 11, 12, 13, 14, 15};
  int off = 0;
  for (int k = 0; k < NSEG; k++) {
    tab.src[k] = d_in[srcIdx[k]];
    tab.off[k] = off;
    off += sizes[k];
  }
  tab.total = off;
  k_cvt_params<<<(off + 255) / 256, 256, 0, stream>>>(tab, pblock, flags);

  // fold relation transforms (both layers, one launch)
  k_eff<<<dim3(CD + 1, HH, LL * 2), DH, 0, stream>>>(pWk, pbk, pWv, pbv, par, pmr,
                                                     wkeff, bkeff, wveff, bveff);

  // CSR by dst (edge list is layer-invariant)
  hipMemsetAsync(deg, 0, (size_t)N * sizeof(int), stream);
  k_hist<<<(E + 255) / 256, 256, 0, stream>>>(ei, deg, flags, E, N);
  k_scan1<<<nB, 256, 0, stream>>>(deg, tmp, bsum, N);
  k_scan2<<<1, 256, 0, stream>>>(bsum, nB);
  k_scan3<<<nB, 256, 0, stream>>>(tmp, deg, bsum, rowptr, fill, N);
  k_scatter<<<(E + 255) / 256, 256, 0, stream>>>(ei, fill, csr_src, flags, E, N);

  const int gemmBlocks = (N + 127) / 128;
  for (int l = 0; l < LL; l++) {
    k_gemm3<<<gemmBlocks, 256, 0, stream>>>(
        hbuf,
        pWq + (size_t)l * CD * CD, pbq + (size_t)l * CD, qbuf,
        wkeff + (size_t)l * CD * CD, bkeff + (size_t)l * CD, kbuf,
        wveff + (size_t)l * CD * CD, bveff + (size_t)l * CD, vbuf, N);

    k_edge<<<(N + 3) / 4, 256, 0, stream>>>(qbuf, kbuf, vbuf, rowptr, deg,
                                            csr_src, ppr + (size_t)l * HH, qbuf, N);

    k_gemm_gate<<<gemmBlocks, 256, 0, stream>>>(
        qbuf, pWa + (size_t)l * CD * CD, pba + (size_t)l * CD, hbuf, pskip + l, N);
  }
  k_final<<<(N + 7) / 8, 256, 0, stream>>>(hbuf, pWfc, pbfc, d_out, flags, N);
}